// Round 2
// baseline (252.636 us; speedup 1.0000x reference)
//
#include <hip/hip_runtime.h>

#define NPOS 16384
#define NEG  (-1e30f)

// workspace offsets (floats)
#define OFF_FWDH  0
#define OFF_BWDH  1966080
#define OFF_A     3932160
#define OFF_T0    4194304
#define OFF_R     4251904
#define OFF_GSC   4255504
#define OFF_CTR   4255744   // 17 x u32 (16 group counters + 1 final)
#define OFF_IND   4255776   // 1 x f32 (indiv sum, written by block 0)

struct Params {
    const float *data, *fWih, *fWhh, *fbih, *fbhh, *bWih, *bWhh, *bbih, *bbhh;
    const float *h0f, *c0f, *h0b, *c0b, *Yenc, *Zenc, *VW, *Vb, *WW, *Wb;
    const int *tags, *lengths;
    float *ws; float *out;
};

typedef _Float16 half2_t __attribute__((ext_vector_type(2)));

__device__ __forceinline__ half2_t u2h(unsigned int v) {
    return __builtin_bit_cast(half2_t, v);
}
__device__ __forceinline__ unsigned int packh(float a, float b) {
    half2_t h = { (_Float16)a, (_Float16)b };
    return __builtin_bit_cast(unsigned int, h);
}
__device__ __forceinline__ float fdot2_(unsigned int w, unsigned int x, float acc) {
    return __builtin_amdgcn_fdot2(u2h(w), u2h(x), acc, false);
}
__device__ __forceinline__ float sigf(float x) {
    return __builtin_amdgcn_rcpf(1.0f + __expf(-x));
}
__device__ __forceinline__ float tanhf_(float x) {
    return 1.0f - 2.0f * __builtin_amdgcn_rcpf(1.0f + __expf(2.0f * x));
}
__device__ __forceinline__ float lse15(const float* tv) {
    float a0 = fmaxf(tv[0], tv[1]),  a1 = fmaxf(tv[2], tv[3]);
    float a2 = fmaxf(tv[4], tv[5]),  a3 = fmaxf(tv[6], tv[7]);
    float a4 = fmaxf(tv[8], tv[9]),  a5 = fmaxf(tv[10], tv[11]);
    float a6 = fmaxf(tv[12], tv[13]);
    float b0 = fmaxf(a0, a1), b1 = fmaxf(a2, a3), b2 = fmaxf(a4, a5), b3 = fmaxf(a6, tv[14]);
    float mx = fmaxf(fmaxf(b0, b1), fmaxf(b2, b3));
    float e[15];
    #pragma unroll
    for (int i = 0; i < 15; i++) e[i] = __expf(tv[i] - mx);
    float s0 = e[0]+e[1], s1 = e[2]+e[3], s2 = e[4]+e[5], s3 = e[6]+e[7];
    float s4 = e[8]+e[9], s5 = e[10]+e[11], s6 = e[12]+e[13];
    float t0 = s0+s1, t1 = s2+s3, t2 = s4+s5, t3 = s6+e[14];
    return mx + __logf((t0+t1) + (t2+t3));
}

// lse-semiring 15x15 matmul, pairwise: dst[m] = src[2m+1] o src[2m]
// matrices stored [mat][i*16 + j] (stride-16 rows: conflict-free column reads)
__device__ __forceinline__ void lse_mm(const float* src, float* dst, int nprod,
                                       int tid, int nthr)
{
    const int tot = nprod * 225;
    for (int e = tid; e < tot; e += nthr) {
        const int m = e / 225;
        const int r = e - m * 225;
        const int i = r / 15;
        const int j = r - i * 15;
        const float* Ar = src + (2*m + 1)*240 + i*16;   // row i of later matrix
        const float* Bc = src + (2*m)*240 + j;          // col j of earlier matrix
        float tv[15];
        #pragma unroll
        for (int k = 0; k < 15; k++) tv[k] = Ar[k] + Bc[k*16];
        dst[m*240 + i*16 + j] = lse15(tv);
    }
}

// ================= kA: fp16-dot2 xg + LSTM ==================================
__global__ __launch_bounds__(512) void kA(Params p)
{
    __shared__ unsigned int xs2[78*33];   // x fp16-pairs [row][k2], stride 33
    __shared__ float xgT[64*78];          // xg f32 [gate][row]
    __shared__ unsigned int hsh[2*512];   // h fp16-pairs [buf][m2*64+lane]
    __shared__ unsigned int wqx[2048];    // Wih pairs [k2][wq*8+jj]
    __shared__ unsigned int wqh[512];     // Whh pairs [m2][wq*8+jj]
    __shared__ float bq[64];

    const int tid  = threadIdx.x;
    const int lane = tid & 63;
    const int wq   = __builtin_amdgcn_readfirstlane(tid >> 6);
    const int dir  = blockIdx.y;
    const int P0   = blockIdx.x << 6;
    const int dbase = P0 - (dir ? 14 : 0);

    if (blockIdx.x == 0 && dir == 0 && tid < 17)
        ((unsigned int*)(p.ws + OFF_CTR))[tid] = 0;

    const float* Wih = dir ? p.bWih : p.fWih;
    const float* Whh = dir ? p.bWhh : p.fWhh;
    const float* bih = dir ? p.bbih : p.fbih;
    const float* bhh = dir ? p.bbhh : p.fbhh;
    const float* h0  = dir ? p.h0b  : p.h0f;
    const float* c0  = dir ? p.c0b  : p.c0f;

    for (int e = tid; e < 2048; e += 512) {
        int k2 = e >> 6, pi = e & 63;
        int w = pi >> 3, jj = pi & 7;
        int j = ((jj >> 1) << 4) + 2*w + (jj & 1);
        wqx[e] = packh(Wih[j*64 + 2*k2], Wih[j*64 + 2*k2 + 1]);
    }
    if (tid < 512) {
        int m2 = tid >> 6, pi = tid & 63;
        int w = pi >> 3, jj = pi & 7;
        int j = ((jj >> 1) << 4) + 2*w + (jj & 1);
        wqh[tid] = packh(Whh[j*16 + 2*m2], Whh[j*16 + 2*m2 + 1]);
    }
    if (tid < 64) {
        int w = tid >> 3, jj = tid & 7;
        int j = ((jj >> 1) << 4) + 2*w + (jj & 1);
        bq[tid] = bih[j] + bhh[j];
    }
    for (int idx = tid; idx < 78*32; idx += 512) {
        int r = idx >> 5, c = idx & 31;
        int q = dbase + r;
        q = q < 0 ? 0 : (q > NPOS-1 ? NPOS-1 : q);
        float2 x2 = *(const float2*)(p.data + (size_t)q*64 + c*2);
        xs2[r*33 + c] = packh(x2.x, x2.y);
    }
    if (tid < 512) {
        int m2 = tid >> 6;
        hsh[tid] = packh(h0[2*m2], h0[2*m2 + 1]);
    }
    __syncthreads();

    #pragma unroll
    for (int pass = 0; pass < 2; pass++) {
        int r = pass*64 + lane;
        if (r < 78) {
            float acc[8];
            #pragma unroll
            for (int jj = 0; jj < 8; jj++) acc[jj] = bq[wq*8 + jj];
            #pragma unroll 8
            for (int k2 = 0; k2 < 32; k2++) {
                unsigned int xp = xs2[r*33 + k2];
                uint4 w0 = *(const uint4*)&wqx[k2*64 + wq*8];
                uint4 w1 = *(const uint4*)&wqx[k2*64 + wq*8 + 4];
                acc[0] = fdot2_(w0.x, xp, acc[0]);
                acc[1] = fdot2_(w0.y, xp, acc[1]);
                acc[2] = fdot2_(w0.z, xp, acc[2]);
                acc[3] = fdot2_(w0.w, xp, acc[3]);
                acc[4] = fdot2_(w1.x, xp, acc[4]);
                acc[5] = fdot2_(w1.y, xp, acc[5]);
                acc[6] = fdot2_(w1.z, xp, acc[6]);
                acc[7] = fdot2_(w1.w, xp, acc[7]);
            }
            #pragma unroll
            for (int jj = 0; jj < 8; jj++) xgT[(wq*8 + jj)*78 + r] = acc[jj];
        }
    }
    float cv0 = c0[wq*2], cv1 = c0[wq*2 + 1];
    unsigned int* outH = (unsigned int*)(p.ws + (dir ? OFF_BWDH : OFF_FWDH));
    __syncthreads();

    int buf = 0;
    for (int d = 0; d < 15; d++) {
        const int row = dir ? (lane + 14 - d) : (lane + d);
        float part[8];
        #pragma unroll
        for (int jj = 0; jj < 8; jj++) part[jj] = xgT[(wq*8 + jj)*78 + row];
        #pragma unroll
        for (int m2 = 0; m2 < 8; m2++) {
            unsigned int hp = hsh[buf*512 + m2*64 + lane];
            uint4 w0 = *(const uint4*)&wqh[m2*64 + wq*8];
            uint4 w1 = *(const uint4*)&wqh[m2*64 + wq*8 + 4];
            part[0] = fdot2_(w0.x, hp, part[0]);
            part[1] = fdot2_(w0.y, hp, part[1]);
            part[2] = fdot2_(w0.z, hp, part[2]);
            part[3] = fdot2_(w0.w, hp, part[3]);
            part[4] = fdot2_(w1.x, hp, part[4]);
            part[5] = fdot2_(w1.y, hp, part[5]);
            part[6] = fdot2_(w1.z, hp, part[6]);
            part[7] = fdot2_(w1.w, hp, part[7]);
        }
        float cn0 = sigf(part[2])*cv0 + sigf(part[0])*tanhf_(part[4]);
        float cn1 = sigf(part[3])*cv1 + sigf(part[1])*tanhf_(part[5]);
        cv0 = cn0; cv1 = cn1;
        float h0v = sigf(part[6])*tanhf_(cn0);
        float h1v = sigf(part[7])*tanhf_(cn1);
        unsigned int pk = packh(h0v, h1v);
        hsh[(buf^1)*512 + wq*64 + lane] = pk;
        outH[((size_t)d*NPOS + P0 + lane)*8 + wq] = pk;
        __syncthreads();
        buf ^= 1;
    }
}

// ======= kBC: scores + chunk DP (tree) + fused group/final combine ==========
// 256 blocks x 1024 thr. Block c: positions [64c, 64c+64), chunk matrix -> T0.
// Group g = c>>4: last arrival in group combines 16 chunk mats -> R[g].
// Last group-finisher combines 16 R mats -> logZ, subtracts indiv, writes out.
__global__ __launch_bounds__(1024) void kBC(Params p)
{
    __shared__ float As[64*17];
    __shared__ unsigned int VWh[256];
    __shared__ float zbl[240];
    __shared__ float EY[240];
    __shared__ float Ms[16*240];
    __shared__ float Mp[8*240];
    __shared__ float gscL[240];          // block 0 only: sc[pp][y], stride 16
    __shared__ float red[16];
    __shared__ int flagS;
    const int tid = threadIdx.x;
    const int P0  = blockIdx.x << 6;
    float* ws = p.ws;
    unsigned int* ctr = (unsigned int*)(ws + OFF_CTR);

    if (tid < 240) {
        int y = tid >> 4, h = tid & 15;
        float acc = 0.f;
        for (int t = 0; t < 32; t++) acc += p.Yenc[y*32 + t] * p.VW[h*68 + 32 + t];
        EY[tid] = __expf(acc + acc);
        float z = p.Vb[h];
        for (int u = 0; u < 4; u++) z += p.Zenc[y*4 + u] * p.VW[h*68 + 64 + u];
        zbl[tid] = z;
    }
    if (tid < 256) {
        int h = tid >> 4, j2 = tid & 15;
        int col = (j2 < 8) ? 2*j2 : 16 + 2*(j2 - 8);
        VWh[tid] = packh(p.VW[h*68 + col], p.VW[h*68 + col + 1]);
    }
    __syncthreads();

    const int pl = tid & 63;
    const int d  = tid >> 6;
    const int pp = P0 + pl;
    float Aval = NEG;
    if (d < 15 && pp >= d) {
        const uint4* fptr = (const uint4*)((const unsigned int*)(ws + OFF_FWDH)
                            + ((size_t)d*NPOS + (pp - d))*8);
        const uint4* bptr = (const uint4*)((const unsigned int*)(ws + OFF_BWDH)
                            + ((size_t)d*NPOS + pp)*8);
        uint4 f0 = fptr[0], f1 = fptr[1];
        uint4 b0 = bptr[0], b1 = bptr[1];
        unsigned int fp_[8] = {f0.x, f0.y, f0.z, f0.w, f1.x, f1.y, f1.z, f1.w};
        unsigned int bp_[8] = {b0.x, b0.y, b0.z, b0.w, b1.x, b1.y, b1.z, b1.w};
        float E[16], w2[16], wsum = 0.f;
        #pragma unroll
        for (int h = 0; h < 16; h++) {
            float acc = zbl[d*16 + h];
            uint4 va = *(const uint4*)&VWh[h*16];
            uint4 vb = *(const uint4*)&VWh[h*16 + 4];
            uint4 vc = *(const uint4*)&VWh[h*16 + 8];
            uint4 vd = *(const uint4*)&VWh[h*16 + 12];
            acc = fdot2_(va.x, fp_[0], acc); acc = fdot2_(va.y, fp_[1], acc);
            acc = fdot2_(va.z, fp_[2], acc); acc = fdot2_(va.w, fp_[3], acc);
            acc = fdot2_(vb.x, fp_[4], acc); acc = fdot2_(vb.y, fp_[5], acc);
            acc = fdot2_(vb.z, fp_[6], acc); acc = fdot2_(vb.w, fp_[7], acc);
            acc = fdot2_(vc.x, bp_[0], acc); acc = fdot2_(vc.y, bp_[1], acc);
            acc = fdot2_(vc.z, bp_[2], acc); acc = fdot2_(vc.w, bp_[3], acc);
            acc = fdot2_(vd.x, bp_[4], acc); acc = fdot2_(vd.y, bp_[5], acc);
            acc = fdot2_(vd.z, bp_[6], acc); acc = fdot2_(vd.w, bp_[7], acc);
            E[h] = __expf(acc + acc);
            float w = p.WW[h];
            w2[h] = -2.0f * w;
            wsum += w;
        }
        const float cst = p.Wb[0] + wsum;
        float sc[15];
        #pragma unroll
        for (int y = 0; y < 15; y++) {
            float a = 0.f;
            #pragma unroll
            for (int h = 0; h < 16; h++)
                a = fmaf(w2[h], __builtin_amdgcn_rcpf(1.0f + E[h]*EY[y*16 + h]), a);
            sc[y] = cst + a;
        }
        Aval = lse15(sc);
        if (pp == d && pp < 15) {
            #pragma unroll
            for (int y = 0; y < 15; y++) gscL[pp*16 + y] = sc[y];
        }
    }
    As[pl*17 + d] = Aval;
    __syncthreads();

    // condensed 4-step transfer matrix per wave (16 waves x 4 steps = 64)
    {
        const int wv = tid >> 6;
        const int ln = tid & 63;
        if (ln < 15) {
            float s[15];
            #pragma unroll
            for (int i = 0; i < 15; i++) s[i] = (i == ln) ? 0.f : NEG;
            const int t0 = wv * 4;
            #pragma unroll
            for (int q = 0; q < 4; q++) {
                const int t = t0 + q;
                float tv[15];
                #pragma unroll
                for (int i = 0; i < 15; i++) tv[i] = s[i] + As[t*17 + i];
                float nw = lse15(tv);
                #pragma unroll
                for (int i = 14; i > 0; i--) s[i] = s[i-1];
                s[0] = nw;
            }
            #pragma unroll
            for (int i = 0; i < 15; i++) Ms[wv*240 + i*16 + ln] = s[i];
        }
    }
    __syncthreads();

    // depth-4 tree combine -> chunk matrix -> T0[block]
    lse_mm(Ms, Mp, 8, tid, 1024);  __syncthreads();
    lse_mm(Mp, Ms, 4, tid, 1024);  __syncthreads();
    lse_mm(Ms, Mp, 2, tid, 1024);  __syncthreads();
    if (tid < 225) {
        const int i = tid / 15, j = tid - (tid / 15) * 15;
        float tv[15];
        #pragma unroll
        for (int k = 0; k < 15; k++) tv[k] = Mp[240 + i*16 + k] + Mp[k*16 + j];
        (ws + OFF_T0)[blockIdx.x*225 + i*15 + j] = lse15(tv);
    }

    // block 0: indiv (gold-score) reduction from LDS gscL -> scalar
    if (blockIdx.x == 0) {
        float loc = 0.f;
        for (int s = tid; s < 2048; s += 1024) {
            int len = p.lengths[s];
            if (len < 15) loc += gscL[(len-1)*16 + p.tags[s]];
        }
        #pragma unroll
        for (int off = 32; off > 0; off >>= 1) loc += __shfl_down(loc, off);
        if ((tid & 63) == 0) red[tid >> 6] = loc;
        __syncthreads();
        if (tid == 0) {
            float ind = 0.f;
            #pragma unroll
            for (int q = 0; q < 16; q++) ind += red[q];
            ws[OFF_IND] = ind;
        }
    }

    // ---- group combine: last arrival in group g folds 16 chunk mats -> R[g]
    const int g = blockIdx.x >> 4;
    __syncthreads();
    __threadfence();
    if (tid == 0) {
        unsigned int old = __hip_atomic_fetch_add(&ctr[g], 1u, __ATOMIC_ACQ_REL,
                                                  __HIP_MEMORY_SCOPE_AGENT);
        flagS = (old == 15u);
    }
    __syncthreads();
    if (!flagS) return;
    __threadfence();

    {
        const float* T0 = ws + OFF_T0;
        for (int idx = tid; idx < 16*225; idx += 1024) {
            int t = idx / 225, r = idx - t*225;
            Ms[t*240 + (r/15)*16 + (r%15)] = T0[((g<<4) + t)*225 + r];
        }
        __syncthreads();
        lse_mm(Ms, Mp, 8, tid, 1024); __syncthreads();
        lse_mm(Mp, Ms, 4, tid, 1024); __syncthreads();
        lse_mm(Ms, Mp, 2, tid, 1024); __syncthreads();
        if (tid < 225) {
            const int i = tid / 15, j = tid - (tid / 15) * 15;
            float tv[15];
            #pragma unroll
            for (int k = 0; k < 15; k++) tv[k] = Mp[240 + i*16 + k] + Mp[k*16 + j];
            ws[OFF_R + g*225 + i*15 + j] = lse15(tv);
        }
    }

    // ---- final combine: last group-finisher folds 16 R mats -> output
    __syncthreads();
    __threadfence();
    if (tid == 0) {
        unsigned int old = __hip_atomic_fetch_add(&ctr[16], 1u, __ATOMIC_ACQ_REL,
                                                  __HIP_MEMORY_SCOPE_AGENT);
        flagS = (old == 15u);
    }
    __syncthreads();
    if (!flagS) return;
    __threadfence();

    {
        const float* Rg = ws + OFF_R;
        for (int idx = tid; idx < 16*225; idx += 1024) {
            int t = idx / 225, r = idx - t*225;
            Ms[t*240 + (r/15)*16 + (r%15)] = Rg[t*225 + r];
        }
        __syncthreads();
        lse_mm(Ms, Mp, 8, tid, 1024); __syncthreads();
        lse_mm(Mp, Ms, 4, tid, 1024); __syncthreads();
        lse_mm(Ms, Mp, 2, tid, 1024); __syncthreads();
        if (tid == 0) {
            float tv[15];
            #pragma unroll
            for (int k = 0; k < 15; k++) tv[k] = Mp[240 + k] + Mp[k*16];
            float logZ = lse15(tv);
            p.out[0] = logZ - ws[OFF_IND];
        }
    }
}

// ================= launcher =================================================
extern "C" void kernel_launch(void* const* d_in, const int* in_sizes, int n_in,
                              void* d_out, int out_size, void* d_ws, size_t ws_size,
                              hipStream_t stream)
{
    Params prm;
    prm.data = (const float*)d_in[0];
    prm.fWih = (const float*)d_in[1];
    prm.fWhh = (const float*)d_in[2];
    prm.fbih = (const float*)d_in[3];
    prm.fbhh = (const float*)d_in[4];
    prm.bWih = (const float*)d_in[5];
    prm.bWhh = (const float*)d_in[6];
    prm.bbih = (const float*)d_in[7];
    prm.bbhh = (const float*)d_in[8];
    prm.h0f  = (const float*)d_in[9];
    prm.c0f  = (const float*)d_in[10];
    prm.h0b  = (const float*)d_in[11];
    prm.c0b  = (const float*)d_in[12];
    prm.Yenc = (const float*)d_in[13];
    prm.Zenc = (const float*)d_in[14];
    prm.VW   = (const float*)d_in[15];
    prm.Vb   = (const float*)d_in[16];
    prm.WW   = (const float*)d_in[17];
    prm.Wb   = (const float*)d_in[18];
    prm.tags    = (const int*)d_in[19];
    prm.lengths = (const int*)d_in[20];
    prm.ws  = (float*)d_ws;
    prm.out = (float*)d_out;

    hipLaunchKernelGGL(kA,  dim3(256, 2), dim3(512),  0, stream, prm);
    hipLaunchKernelGGL(kBC, dim3(256),    dim3(1024), 0, stream, prm);
}

// Round 3
// 165.526 us; speedup vs baseline: 1.5263x; 1.5263x over previous
//
#include <hip/hip_runtime.h>

#define NPOS 16384
#define NEG  (-1e30f)

// workspace offsets (floats)
#define OFF_FWDH  0
#define OFF_BWDH  1966080
#define OFF_A     3932160
#define OFF_T0    4194304
#define OFF_R     4251904
#define OFF_GSC   4255504
#define OFF_CTR   4255744
#define OFF_IND   4255776   // 1 x f32 (indiv sum, written by kBC block 0)

struct Params {
    const float *data, *fWih, *fWhh, *fbih, *fbhh, *bWih, *bWhh, *bbih, *bbhh;
    const float *h0f, *c0f, *h0b, *c0b, *Yenc, *Zenc, *VW, *Vb, *WW, *Wb;
    const int *tags, *lengths;
    float *ws; float *out;
};

typedef _Float16 half2_t __attribute__((ext_vector_type(2)));

__device__ __forceinline__ half2_t u2h(unsigned int v) {
    return __builtin_bit_cast(half2_t, v);
}
__device__ __forceinline__ unsigned int packh(float a, float b) {
    half2_t h = { (_Float16)a, (_Float16)b };
    return __builtin_bit_cast(unsigned int, h);
}
__device__ __forceinline__ float fdot2_(unsigned int w, unsigned int x, float acc) {
    return __builtin_amdgcn_fdot2(u2h(w), u2h(x), acc, false);
}
__device__ __forceinline__ float sigf(float x) {
    return __builtin_amdgcn_rcpf(1.0f + __expf(-x));
}
__device__ __forceinline__ float tanhf_(float x) {
    return 1.0f - 2.0f * __builtin_amdgcn_rcpf(1.0f + __expf(2.0f * x));
}
__device__ __forceinline__ float lse15(const float* tv) {
    float a0 = fmaxf(tv[0], tv[1]),  a1 = fmaxf(tv[2], tv[3]);
    float a2 = fmaxf(tv[4], tv[5]),  a3 = fmaxf(tv[6], tv[7]);
    float a4 = fmaxf(tv[8], tv[9]),  a5 = fmaxf(tv[10], tv[11]);
    float a6 = fmaxf(tv[12], tv[13]);
    float b0 = fmaxf(a0, a1), b1 = fmaxf(a2, a3), b2 = fmaxf(a4, a5), b3 = fmaxf(a6, tv[14]);
    float mx = fmaxf(fmaxf(b0, b1), fmaxf(b2, b3));
    float e[15];
    #pragma unroll
    for (int i = 0; i < 15; i++) e[i] = __expf(tv[i] - mx);
    float s0 = e[0]+e[1], s1 = e[2]+e[3], s2 = e[4]+e[5], s3 = e[6]+e[7];
    float s4 = e[8]+e[9], s5 = e[10]+e[11], s6 = e[12]+e[13];
    float t0 = s0+s1, t1 = s2+s3, t2 = s4+s5, t3 = s6+e[14];
    return mx + __logf((t0+t1) + (t2+t3));
}

// lse-semiring 15x15 matmul, pairwise: dst[m] = src[2m+1] o src[2m]
// matrices stored [mat][i*16 + j] (stride-16 rows: conflict-free column reads)
__device__ __forceinline__ void lse_mm(const float* src, float* dst, int nprod,
                                       int tid, int nthr)
{
    const int tot = nprod * 225;
    for (int e = tid; e < tot; e += nthr) {
        const int m = e / 225;
        const int r = e - m * 225;
        const int i = r / 15;
        const int j = r - i * 15;
        const float* Ar = src + (2*m + 1)*240 + i*16;   // row i of later matrix
        const float* Bc = src + (2*m)*240 + j;          // col j of earlier matrix
        float tv[15];
        #pragma unroll
        for (int k = 0; k < 15; k++) tv[k] = Ar[k] + Bc[k*16];
        dst[m*240 + i*16 + j] = lse15(tv);
    }
}

// ================= kA: fp16-dot2 xg + LSTM ==================================
__global__ __launch_bounds__(512) void kA(Params p)
{
    __shared__ unsigned int xs2[78*33];   // x fp16-pairs [row][k2], stride 33
    __shared__ float xgT[64*78];          // xg f32 [gate][row]
    __shared__ unsigned int hsh[2*512];   // h fp16-pairs [buf][m2*64+lane]
    __shared__ unsigned int wqx[2048];    // Wih pairs [k2][wq*8+jj]
    __shared__ unsigned int wqh[512];     // Whh pairs [m2][wq*8+jj]
    __shared__ float bq[64];

    const int tid  = threadIdx.x;
    const int lane = tid & 63;
    const int wq   = __builtin_amdgcn_readfirstlane(tid >> 6);
    const int dir  = blockIdx.y;
    const int P0   = blockIdx.x << 6;
    const int dbase = P0 - (dir ? 14 : 0);

    const float* Wih = dir ? p.bWih : p.fWih;
    const float* Whh = dir ? p.bWhh : p.fWhh;
    const float* bih = dir ? p.bbih : p.fbih;
    const float* bhh = dir ? p.bbhh : p.fbhh;
    const float* h0  = dir ? p.h0b  : p.h0f;
    const float* c0  = dir ? p.c0b  : p.c0f;

    for (int e = tid; e < 2048; e += 512) {
        int k2 = e >> 6, pi = e & 63;
        int w = pi >> 3, jj = pi & 7;
        int j = ((jj >> 1) << 4) + 2*w + (jj & 1);
        wqx[e] = packh(Wih[j*64 + 2*k2], Wih[j*64 + 2*k2 + 1]);
    }
    if (tid < 512) {
        int m2 = tid >> 6, pi = tid & 63;
        int w = pi >> 3, jj = pi & 7;
        int j = ((jj >> 1) << 4) + 2*w + (jj & 1);
        wqh[tid] = packh(Whh[j*16 + 2*m2], Whh[j*16 + 2*m2 + 1]);
    }
    if (tid < 64) {
        int w = tid >> 3, jj = tid & 7;
        int j = ((jj >> 1) << 4) + 2*w + (jj & 1);
        bq[tid] = bih[j] + bhh[j];
    }
    for (int idx = tid; idx < 78*32; idx += 512) {
        int r = idx >> 5, c = idx & 31;
        int q = dbase + r;
        q = q < 0 ? 0 : (q > NPOS-1 ? NPOS-1 : q);
        float2 x2 = *(const float2*)(p.data + (size_t)q*64 + c*2);
        xs2[r*33 + c] = packh(x2.x, x2.y);
    }
    if (tid < 512) {
        int m2 = tid >> 6;
        hsh[tid] = packh(h0[2*m2], h0[2*m2 + 1]);
    }
    __syncthreads();

    #pragma unroll
    for (int pass = 0; pass < 2; pass++) {
        int r = pass*64 + lane;
        if (r < 78) {
            float acc[8];
            #pragma unroll
            for (int jj = 0; jj < 8; jj++) acc[jj] = bq[wq*8 + jj];
            #pragma unroll 8
            for (int k2 = 0; k2 < 32; k2++) {
                unsigned int xp = xs2[r*33 + k2];
                uint4 w0 = *(const uint4*)&wqx[k2*64 + wq*8];
                uint4 w1 = *(const uint4*)&wqx[k2*64 + wq*8 + 4];
                acc[0] = fdot2_(w0.x, xp, acc[0]);
                acc[1] = fdot2_(w0.y, xp, acc[1]);
                acc[2] = fdot2_(w0.z, xp, acc[2]);
                acc[3] = fdot2_(w0.w, xp, acc[3]);
                acc[4] = fdot2_(w1.x, xp, acc[4]);
                acc[5] = fdot2_(w1.y, xp, acc[5]);
                acc[6] = fdot2_(w1.z, xp, acc[6]);
                acc[7] = fdot2_(w1.w, xp, acc[7]);
            }
            #pragma unroll
            for (int jj = 0; jj < 8; jj++) xgT[(wq*8 + jj)*78 + r] = acc[jj];
        }
    }
    float cv0 = c0[wq*2], cv1 = c0[wq*2 + 1];
    unsigned int* outH = (unsigned int*)(p.ws + (dir ? OFF_BWDH : OFF_FWDH));
    __syncthreads();

    int buf = 0;
    for (int d = 0; d < 15; d++) {
        const int row = dir ? (lane + 14 - d) : (lane + d);
        float part[8];
        #pragma unroll
        for (int jj = 0; jj < 8; jj++) part[jj] = xgT[(wq*8 + jj)*78 + row];
        #pragma unroll
        for (int m2 = 0; m2 < 8; m2++) {
            unsigned int hp = hsh[buf*512 + m2*64 + lane];
            uint4 w0 = *(const uint4*)&wqh[m2*64 + wq*8];
            uint4 w1 = *(const uint4*)&wqh[m2*64 + wq*8 + 4];
            part[0] = fdot2_(w0.x, hp, part[0]);
            part[1] = fdot2_(w0.y, hp, part[1]);
            part[2] = fdot2_(w0.z, hp, part[2]);
            part[3] = fdot2_(w0.w, hp, part[3]);
            part[4] = fdot2_(w1.x, hp, part[4]);
            part[5] = fdot2_(w1.y, hp, part[5]);
            part[6] = fdot2_(w1.z, hp, part[6]);
            part[7] = fdot2_(w1.w, hp, part[7]);
        }
        float cn0 = sigf(part[2])*cv0 + sigf(part[0])*tanhf_(part[4]);
        float cn1 = sigf(part[3])*cv1 + sigf(part[1])*tanhf_(part[5]);
        cv0 = cn0; cv1 = cn1;
        float h0v = sigf(part[6])*tanhf_(cn0);
        float h1v = sigf(part[7])*tanhf_(cn1);
        unsigned int pk = packh(h0v, h1v);
        hsh[(buf^1)*512 + wq*64 + lane] = pk;
        outH[((size_t)d*NPOS + P0 + lane)*8 + wq] = pk;
        __syncthreads();
        buf ^= 1;
    }
}

// ================= kBC: scores + chunk DP (tree) — fence-free ===============
// 256 blocks x 1024 thr. Block c: positions [64c, 64c+64), chunk matrix -> T0.
// Block 0 additionally reduces the gold scores (in LDS) -> ws[OFF_IND].
__global__ __launch_bounds__(1024) void kBC(Params p)
{
    __shared__ float As[64*17];
    __shared__ unsigned int VWh[256];
    __shared__ float zbl[240];
    __shared__ float EY[240];
    __shared__ float Ms[16*240];
    __shared__ float Mp[8*240];
    __shared__ float gscL[240];          // block 0 only: sc[pp][y], stride 16
    __shared__ float red[16];
    const int tid = threadIdx.x;
    const int P0  = blockIdx.x << 6;
    float* ws = p.ws;

    if (tid < 240) {
        int y = tid >> 4, h = tid & 15;
        float acc = 0.f;
        for (int t = 0; t < 32; t++) acc += p.Yenc[y*32 + t] * p.VW[h*68 + 32 + t];
        EY[tid] = __expf(acc + acc);
        float z = p.Vb[h];
        for (int u = 0; u < 4; u++) z += p.Zenc[y*4 + u] * p.VW[h*68 + 64 + u];
        zbl[tid] = z;
    }
    if (tid < 256) {
        int h = tid >> 4, j2 = tid & 15;
        int col = (j2 < 8) ? 2*j2 : 16 + 2*(j2 - 8);
        VWh[tid] = packh(p.VW[h*68 + col], p.VW[h*68 + col + 1]);
    }
    __syncthreads();

    const int pl = tid & 63;
    const int d  = tid >> 6;
    const int pp = P0 + pl;
    float Aval = NEG;
    if (d < 15 && pp >= d) {
        const uint4* fptr = (const uint4*)((const unsigned int*)(ws + OFF_FWDH)
                            + ((size_t)d*NPOS + (pp - d))*8);
        const uint4* bptr = (const uint4*)((const unsigned int*)(ws + OFF_BWDH)
                            + ((size_t)d*NPOS + pp)*8);
        uint4 f0 = fptr[0], f1 = fptr[1];
        uint4 b0 = bptr[0], b1 = bptr[1];
        unsigned int fp_[8] = {f0.x, f0.y, f0.z, f0.w, f1.x, f1.y, f1.z, f1.w};
        unsigned int bp_[8] = {b0.x, b0.y, b0.z, b0.w, b1.x, b1.y, b1.z, b1.w};
        float E[16], w2[16], wsum = 0.f;
        #pragma unroll
        for (int h = 0; h < 16; h++) {
            float acc = zbl[d*16 + h];
            uint4 va = *(const uint4*)&VWh[h*16];
            uint4 vb = *(const uint4*)&VWh[h*16 + 4];
            uint4 vc = *(const uint4*)&VWh[h*16 + 8];
            uint4 vd = *(const uint4*)&VWh[h*16 + 12];
            acc = fdot2_(va.x, fp_[0], acc); acc = fdot2_(va.y, fp_[1], acc);
            acc = fdot2_(va.z, fp_[2], acc); acc = fdot2_(va.w, fp_[3], acc);
            acc = fdot2_(vb.x, fp_[4], acc); acc = fdot2_(vb.y, fp_[5], acc);
            acc = fdot2_(vb.z, fp_[6], acc); acc = fdot2_(vb.w, fp_[7], acc);
            acc = fdot2_(vc.x, bp_[0], acc); acc = fdot2_(vc.y, bp_[1], acc);
            acc = fdot2_(vc.z, bp_[2], acc); acc = fdot2_(vc.w, bp_[3], acc);
            acc = fdot2_(vd.x, bp_[4], acc); acc = fdot2_(vd.y, bp_[5], acc);
            acc = fdot2_(vd.z, bp_[6], acc); acc = fdot2_(vd.w, bp_[7], acc);
            E[h] = __expf(acc + acc);
            float w = p.WW[h];
            w2[h] = -2.0f * w;
            wsum += w;
        }
        const float cst = p.Wb[0] + wsum;
        float sc[15];
        #pragma unroll
        for (int y = 0; y < 15; y++) {
            float a = 0.f;
            #pragma unroll
            for (int h = 0; h < 16; h++)
                a = fmaf(w2[h], __builtin_amdgcn_rcpf(1.0f + E[h]*EY[y*16 + h]), a);
            sc[y] = cst + a;
        }
        Aval = lse15(sc);
        if (pp == d && pp < 15) {
            #pragma unroll
            for (int y = 0; y < 15; y++) gscL[pp*16 + y] = sc[y];
        }
    }
    As[pl*17 + d] = Aval;
    __syncthreads();

    // condensed 4-step transfer matrix per wave (16 waves x 4 steps = 64)
    {
        const int wv = tid >> 6;
        const int ln = tid & 63;
        if (ln < 15) {
            float s[15];
            #pragma unroll
            for (int i = 0; i < 15; i++) s[i] = (i == ln) ? 0.f : NEG;
            const int t0 = wv * 4;
            #pragma unroll
            for (int q = 0; q < 4; q++) {
                const int t = t0 + q;
                float tv[15];
                #pragma unroll
                for (int i = 0; i < 15; i++) tv[i] = s[i] + As[t*17 + i];
                float nw = lse15(tv);
                #pragma unroll
                for (int i = 14; i > 0; i--) s[i] = s[i-1];
                s[0] = nw;
            }
            #pragma unroll
            for (int i = 0; i < 15; i++) Ms[wv*240 + i*16 + ln] = s[i];
        }
    }
    __syncthreads();

    // depth-4 tree combine -> chunk matrix -> T0[block]
    lse_mm(Ms, Mp, 8, tid, 1024);  __syncthreads();
    lse_mm(Mp, Ms, 4, tid, 1024);  __syncthreads();
    lse_mm(Ms, Mp, 2, tid, 1024);  __syncthreads();
    if (tid < 225) {
        const int i = tid / 15, j = tid - (tid / 15) * 15;
        float tv[15];
        #pragma unroll
        for (int k = 0; k < 15; k++) tv[k] = Mp[240 + i*16 + k] + Mp[k*16 + j];
        (ws + OFF_T0)[blockIdx.x*225 + i*15 + j] = lse15(tv);
    }

    // block 0: indiv (gold-score) reduction from LDS gscL -> scalar
    if (blockIdx.x == 0) {
        float loc = 0.f;
        for (int s = tid; s < 2048; s += 1024) {
            int len = p.lengths[s];
            if (len < 15) loc += gscL[(len-1)*16 + p.tags[s]];
        }
        #pragma unroll
        for (int off = 32; off > 0; off >>= 1) loc += __shfl_down(loc, off);
        if ((tid & 63) == 0) red[tid >> 6] = loc;
        __syncthreads();
        if (tid == 0) {
            float ind = 0.f;
            #pragma unroll
            for (int q = 0; q < 16; q++) ind += red[q];
            ws[OFF_IND] = ind;
        }
    }
}

// ============ kD: 16 blocks, group combine (fence-free) =====================
__global__ __launch_bounds__(1024) void kD(Params p)
{
    __shared__ float Ms[16*240];
    __shared__ float Mp[8*240];
    const int tid = threadIdx.x;
    const int g   = blockIdx.x;
    const float* T0 = p.ws + OFF_T0;

    for (int idx = tid; idx < 16*225; idx += 1024) {
        int t = idx / 225, r = idx - t*225;
        Ms[t*240 + (r/15)*16 + (r%15)] = T0[((g<<4) + t)*225 + r];
    }
    __syncthreads();
    lse_mm(Ms, Mp, 8, tid, 1024); __syncthreads();
    lse_mm(Mp, Ms, 4, tid, 1024); __syncthreads();
    lse_mm(Ms, Mp, 2, tid, 1024); __syncthreads();
    if (tid < 225) {
        const int i = tid / 15, j = tid - (tid / 15) * 15;
        float tv[15];
        #pragma unroll
        for (int k = 0; k < 15; k++) tv[k] = Mp[240 + i*16 + k] + Mp[k*16 + j];
        p.ws[OFF_R + g*225 + i*15 + j] = lse15(tv);
    }
}

// ============ kE: 1 block, final combine + output (fence-free) ==============
__global__ __launch_bounds__(1024) void kE(Params p)
{
    __shared__ float Ms[16*240];
    __shared__ float Mp[8*240];
    const int tid = threadIdx.x;
    const float* Rg = p.ws + OFF_R;

    for (int idx = tid; idx < 16*225; idx += 1024) {
        int t = idx / 225, r = idx - t*225;
        Ms[t*240 + (r/15)*16 + (r%15)] = Rg[t*225 + r];
    }
    __syncthreads();
    lse_mm(Ms, Mp, 8, tid, 1024); __syncthreads();
    lse_mm(Mp, Ms, 4, tid, 1024); __syncthreads();
    lse_mm(Ms, Mp, 2, tid, 1024); __syncthreads();
    if (tid == 0) {
        float tv[15];
        #pragma unroll
        for (int k = 0; k < 15; k++) tv[k] = Mp[240 + k] + Mp[k*16];
        float logZ = lse15(tv);
        p.out[0] = logZ - p.ws[OFF_IND];
    }
}

// ================= launcher =================================================
extern "C" void kernel_launch(void* const* d_in, const int* in_sizes, int n_in,
                              void* d_out, int out_size, void* d_ws, size_t ws_size,
                              hipStream_t stream)
{
    Params prm;
    prm.data = (const float*)d_in[0];
    prm.fWih = (const float*)d_in[1];
    prm.fWhh = (const float*)d_in[2];
    prm.fbih = (const float*)d_in[3];
    prm.fbhh = (const float*)d_in[4];
    prm.bWih = (const float*)d_in[5];
    prm.bWhh = (const float*)d_in[6];
    prm.bbih = (const float*)d_in[7];
    prm.bbhh = (const float*)d_in[8];
    prm.h0f  = (const float*)d_in[9];
    prm.c0f  = (const float*)d_in[10];
    prm.h0b  = (const float*)d_in[11];
    prm.c0b  = (const float*)d_in[12];
    prm.Yenc = (const float*)d_in[13];
    prm.Zenc = (const float*)d_in[14];
    prm.VW   = (const float*)d_in[15];
    prm.Vb   = (const float*)d_in[16];
    prm.WW   = (const float*)d_in[17];
    prm.Wb   = (const float*)d_in[18];
    prm.tags    = (const int*)d_in[19];
    prm.lengths = (const int*)d_in[20];
    prm.ws  = (float*)d_ws;
    prm.out = (float*)d_out;

    hipLaunchKernelGGL(kA,  dim3(256, 2), dim3(512),  0, stream, prm);
    hipLaunchKernelGGL(kBC, dim3(256),    dim3(1024), 0, stream, prm);
    hipLaunchKernelGGL(kD,  dim3(16),     dim3(1024), 0, stream, prm);
    hipLaunchKernelGGL(kE,  dim3(1),      dim3(1024), 0, stream, prm);
}

// Round 4
// 163.577 us; speedup vs baseline: 1.5445x; 1.0119x over previous
//
#include <hip/hip_runtime.h>

#define NPOS 16384
#define NEG  (-1e30f)

// workspace offsets (floats)
#define OFF_FWDH  0
#define OFF_BWDH  1966080
#define OFF_T0    4194304
#define OFF_R     4251904
#define OFF_IND   4255776   // 1 x f32 (indiv sum, written by kBC block 0)

struct Params {
    const float *data, *fWih, *fWhh, *fbih, *fbhh, *bWih, *bWhh, *bbih, *bbhh;
    const float *h0f, *c0f, *h0b, *c0b, *Yenc, *Zenc, *VW, *Vb, *WW, *Wb;
    const int *tags, *lengths;
    float *ws; float *out;
};

typedef _Float16 half2_t __attribute__((ext_vector_type(2)));

__device__ __forceinline__ half2_t u2h(unsigned int v) {
    return __builtin_bit_cast(half2_t, v);
}
__device__ __forceinline__ unsigned int packh(float a, float b) {
    half2_t h = { (_Float16)a, (_Float16)b };
    return __builtin_bit_cast(unsigned int, h);
}
__device__ __forceinline__ float fdot2_(unsigned int w, unsigned int x, float acc) {
    return __builtin_amdgcn_fdot2(u2h(w), u2h(x), acc, false);
}
__device__ __forceinline__ float sigf(float x) {
    return __builtin_amdgcn_rcpf(1.0f + __expf(-x));
}
__device__ __forceinline__ float tanhf_(float x) {
    return 1.0f - 2.0f * __builtin_amdgcn_rcpf(1.0f + __expf(2.0f * x));
}
__device__ __forceinline__ float lse15(const float* tv) {
    float a0 = fmaxf(tv[0], tv[1]),  a1 = fmaxf(tv[2], tv[3]);
    float a2 = fmaxf(tv[4], tv[5]),  a3 = fmaxf(tv[6], tv[7]);
    float a4 = fmaxf(tv[8], tv[9]),  a5 = fmaxf(tv[10], tv[11]);
    float a6 = fmaxf(tv[12], tv[13]);
    float b0 = fmaxf(a0, a1), b1 = fmaxf(a2, a3), b2 = fmaxf(a4, a5), b3 = fmaxf(a6, tv[14]);
    float mx = fmaxf(fmaxf(b0, b1), fmaxf(b2, b3));
    float e[15];
    #pragma unroll
    for (int i = 0; i < 15; i++) e[i] = __expf(tv[i] - mx);
    float s0 = e[0]+e[1], s1 = e[2]+e[3], s2 = e[4]+e[5], s3 = e[6]+e[7];
    float s4 = e[8]+e[9], s5 = e[10]+e[11], s6 = e[12]+e[13];
    float t0 = s0+s1, t1 = s2+s3, t2 = s4+s5, t3 = s6+e[14];
    return mx + __logf((t0+t1) + (t2+t3));
}

// lse-semiring 15x15 matmul, pairwise: dst[m] = src[2m+1] o src[2m]
// matrices stored [mat][i*16 + j] (stride-16 rows: conflict-free column reads)
__device__ __forceinline__ void lse_mm(const float* src, float* dst, int nprod,
                                       int tid, int nthr)
{
    const int tot = nprod * 225;
    for (int e = tid; e < tot; e += nthr) {
        const int m = e / 225;
        const int r = e - m * 225;
        const int i = r / 15;
        const int j = r - i * 15;
        const float* Ar = src + (2*m + 1)*240 + i*16;   // row i of later matrix
        const float* Bc = src + (2*m)*240 + j;          // col j of earlier matrix
        float tv[15];
        #pragma unroll
        for (int k = 0; k < 15; k++) tv[k] = Ar[k] + Bc[k*16];
        dst[m*240 + i*16 + j] = lse15(tv);
    }
}

// ================= kA: fp16-dot2 xg + LSTM ==================================
__global__ __launch_bounds__(512) void kA(Params p)
{
    __shared__ unsigned int xs2[78*33];   // x fp16-pairs [row][k2], stride 33
    __shared__ float xgT[64*78];          // xg f32 [gate][row]
    __shared__ unsigned int hsh[2*512];   // h fp16-pairs [buf][m2*64+lane]
    __shared__ unsigned int wqx[2048];    // Wih pairs [k2][wq*8+jj]
    __shared__ unsigned int wqh[512];     // Whh pairs [m2][wq*8+jj]
    __shared__ float bq[64];

    const int tid  = threadIdx.x;
    const int lane = tid & 63;
    const int wq   = __builtin_amdgcn_readfirstlane(tid >> 6);
    const int dir  = blockIdx.y;
    const int P0   = blockIdx.x << 6;
    const int dbase = P0 - (dir ? 14 : 0);

    const float* Wih = dir ? p.bWih : p.fWih;
    const float* Whh = dir ? p.bWhh : p.fWhh;
    const float* bih = dir ? p.bbih : p.fbih;
    const float* bhh = dir ? p.bbhh : p.fbhh;
    const float* h0  = dir ? p.h0b  : p.h0f;
    const float* c0  = dir ? p.c0b  : p.c0f;

    for (int e = tid; e < 2048; e += 512) {
        int k2 = e >> 6, pi = e & 63;
        int w = pi >> 3, jj = pi & 7;
        int j = ((jj >> 1) << 4) + 2*w + (jj & 1);
        wqx[e] = packh(Wih[j*64 + 2*k2], Wih[j*64 + 2*k2 + 1]);
    }
    if (tid < 512) {
        int m2 = tid >> 6, pi = tid & 63;
        int w = pi >> 3, jj = pi & 7;
        int j = ((jj >> 1) << 4) + 2*w + (jj & 1);
        wqh[tid] = packh(Whh[j*16 + 2*m2], Whh[j*16 + 2*m2 + 1]);
    }
    if (tid < 64) {
        int w = tid >> 3, jj = tid & 7;
        int j = ((jj >> 1) << 4) + 2*w + (jj & 1);
        bq[tid] = bih[j] + bhh[j];
    }
    for (int idx = tid; idx < 78*32; idx += 512) {
        int r = idx >> 5, c = idx & 31;
        int q = dbase + r;
        q = q < 0 ? 0 : (q > NPOS-1 ? NPOS-1 : q);
        float2 x2 = *(const float2*)(p.data + (size_t)q*64 + c*2);
        xs2[r*33 + c] = packh(x2.x, x2.y);
    }
    if (tid < 512) {
        int m2 = tid >> 6;
        hsh[tid] = packh(h0[2*m2], h0[2*m2 + 1]);
    }
    __syncthreads();

    // xg rows 0..63: thread (wq,lane) -> row=lane, 8 gate-cols (full waves)
    {
        float acc[8];
        #pragma unroll
        for (int jj = 0; jj < 8; jj++) acc[jj] = bq[wq*8 + jj];
        #pragma unroll 8
        for (int k2 = 0; k2 < 32; k2++) {
            unsigned int xp = xs2[lane*33 + k2];
            uint4 w0 = *(const uint4*)&wqx[k2*64 + wq*8];
            uint4 w1 = *(const uint4*)&wqx[k2*64 + wq*8 + 4];
            acc[0] = fdot2_(w0.x, xp, acc[0]);
            acc[1] = fdot2_(w0.y, xp, acc[1]);
            acc[2] = fdot2_(w0.z, xp, acc[2]);
            acc[3] = fdot2_(w0.w, xp, acc[3]);
            acc[4] = fdot2_(w1.x, xp, acc[4]);
            acc[5] = fdot2_(w1.y, xp, acc[5]);
            acc[6] = fdot2_(w1.z, xp, acc[6]);
            acc[7] = fdot2_(w1.w, xp, acc[7]);
        }
        #pragma unroll
        for (int jj = 0; jj < 8; jj++) xgT[(wq*8 + jj)*78 + lane] = acc[jj];
    }
    // xg rows 64..77: 14 rows x 64 gate-cols = 896 single-gate items over
    // 512 threads (2 items/thread) — full lane utilization, no divergence.
    // row = 64+(e>>6) is wave-uniform; gate = lane -> conflict-free wqx reads.
    #pragma unroll
    for (int it = 0; it < 2; it++) {
        int e = tid + it*512;
        if (e < 896) {
            int rw = 64 + (e >> 6);
            int g  = e & 63;
            float acc = bq[g];
            #pragma unroll 8
            for (int k2 = 0; k2 < 32; k2++)
                acc = fdot2_(wqx[k2*64 + g], xs2[rw*33 + k2], acc);
            xgT[g*78 + rw] = acc;
        }
    }
    float cv0 = c0[wq*2], cv1 = c0[wq*2 + 1];
    unsigned int* outH = (unsigned int*)(p.ws + (dir ? OFF_BWDH : OFF_FWDH));
    __syncthreads();

    int buf = 0;
    for (int d = 0; d < 15; d++) {
        const int row = dir ? (lane + 14 - d) : (lane + d);
        float part[8];
        #pragma unroll
        for (int jj = 0; jj < 8; jj++) part[jj] = xgT[(wq*8 + jj)*78 + row];
        #pragma unroll
        for (int m2 = 0; m2 < 8; m2++) {
            unsigned int hp = hsh[buf*512 + m2*64 + lane];
            uint4 w0 = *(const uint4*)&wqh[m2*64 + wq*8];
            uint4 w1 = *(const uint4*)&wqh[m2*64 + wq*8 + 4];
            part[0] = fdot2_(w0.x, hp, part[0]);
            part[1] = fdot2_(w0.y, hp, part[1]);
            part[2] = fdot2_(w0.z, hp, part[2]);
            part[3] = fdot2_(w0.w, hp, part[3]);
            part[4] = fdot2_(w1.x, hp, part[4]);
            part[5] = fdot2_(w1.y, hp, part[5]);
            part[6] = fdot2_(w1.z, hp, part[6]);
            part[7] = fdot2_(w1.w, hp, part[7]);
        }
        float cn0 = sigf(part[2])*cv0 + sigf(part[0])*tanhf_(part[4]);
        float cn1 = sigf(part[3])*cv1 + sigf(part[1])*tanhf_(part[5]);
        cv0 = cn0; cv1 = cn1;
        float h0v = sigf(part[6])*tanhf_(cn0);
        float h1v = sigf(part[7])*tanhf_(cn1);
        unsigned int pk = packh(h0v, h1v);
        hsh[(buf^1)*512 + wq*64 + lane] = pk;
        outH[((size_t)d*NPOS + P0 + lane)*8 + wq] = pk;
        __syncthreads();
        buf ^= 1;
    }
}

// ================= kBC: scores + chunk DP (tree) — fence-free ===============
// 256 blocks x 1024 thr. Block c: positions [64c, 64c+64), chunk matrix -> T0.
// Block 0 additionally reduces the gold scores (in LDS) -> ws[OFF_IND].
__global__ __launch_bounds__(1024) void kBC(Params p)
{
    __shared__ float As[64*17];
    __shared__ unsigned int VWh[256];
    __shared__ float zbl[240];
    __shared__ float EY[240];
    __shared__ float Ms[16*240];
    __shared__ float Mp[8*240];
    __shared__ float gscL[240];          // block 0 only: sc[pp][y], stride 16
    __shared__ float red[16];
    const int tid = threadIdx.x;
    const int P0  = blockIdx.x << 6;
    float* ws = p.ws;

    if (tid < 240) {
        int y = tid >> 4, h = tid & 15;
        const float4* Y4 = (const float4*)(p.Yenc + y*32);
        const float4* V4 = (const float4*)(p.VW + h*68 + 32);   // 16B-aligned
        float acc = 0.f;
        #pragma unroll
        for (int t = 0; t < 8; t++) {
            float4 a = Y4[t], b = V4[t];
            acc += a.x*b.x + a.y*b.y + a.z*b.z + a.w*b.w;
        }
        EY[tid] = __expf(acc + acc);
        float4 z4 = *(const float4*)(p.Zenc + y*4);
        float4 v3 = *(const float4*)(p.VW + h*68 + 64);         // 16B-aligned
        zbl[tid] = p.Vb[h] + z4.x*v3.x + z4.y*v3.y + z4.z*v3.z + z4.w*v3.w;
    }
    if (tid < 256) {
        int h = tid >> 4, j2 = tid & 15;
        int col = (j2 < 8) ? 2*j2 : 16 + 2*(j2 - 8);
        VWh[tid] = packh(p.VW[h*68 + col], p.VW[h*68 + col + 1]);
    }
    __syncthreads();

    const int pl = tid & 63;
    const int d  = tid >> 6;
    const int pp = P0 + pl;
    float Aval = NEG;
    if (d < 15 && pp >= d) {
        const uint4* fptr = (const uint4*)((const unsigned int*)(ws + OFF_FWDH)
                            + ((size_t)d*NPOS + (pp - d))*8);
        const uint4* bptr = (const uint4*)((const unsigned int*)(ws + OFF_BWDH)
                            + ((size_t)d*NPOS + pp)*8);
        uint4 f0 = fptr[0], f1 = fptr[1];
        uint4 b0 = bptr[0], b1 = bptr[1];
        unsigned int fp_[8] = {f0.x, f0.y, f0.z, f0.w, f1.x, f1.y, f1.z, f1.w};
        unsigned int bp_[8] = {b0.x, b0.y, b0.z, b0.w, b1.x, b1.y, b1.z, b1.w};
        float E[16], w2[16], wsum = 0.f;
        #pragma unroll
        for (int h = 0; h < 16; h++) {
            float acc = zbl[d*16 + h];
            uint4 va = *(const uint4*)&VWh[h*16];
            uint4 vb = *(const uint4*)&VWh[h*16 + 4];
            uint4 vc = *(const uint4*)&VWh[h*16 + 8];
            uint4 vd = *(const uint4*)&VWh[h*16 + 12];
            acc = fdot2_(va.x, fp_[0], acc); acc = fdot2_(va.y, fp_[1], acc);
            acc = fdot2_(va.z, fp_[2], acc); acc = fdot2_(va.w, fp_[3], acc);
            acc = fdot2_(vb.x, fp_[4], acc); acc = fdot2_(vb.y, fp_[5], acc);
            acc = fdot2_(vb.z, fp_[6], acc); acc = fdot2_(vb.w, fp_[7], acc);
            acc = fdot2_(vc.x, bp_[0], acc); acc = fdot2_(vc.y, bp_[1], acc);
            acc = fdot2_(vc.z, bp_[2], acc); acc = fdot2_(vc.w, bp_[3], acc);
            acc = fdot2_(vd.x, bp_[4], acc); acc = fdot2_(vd.y, bp_[5], acc);
            acc = fdot2_(vd.z, bp_[6], acc); acc = fdot2_(vd.w, bp_[7], acc);
            E[h] = __expf(acc + acc);
            float w = p.WW[h];
            w2[h] = -2.0f * w;
            wsum += w;
        }
        const float cst = p.Wb[0] + wsum;
        float sc[15];
        #pragma unroll
        for (int y = 0; y < 15; y++) {
            float a = 0.f;
            #pragma unroll
            for (int h = 0; h < 16; h++)
                a = fmaf(w2[h], __builtin_amdgcn_rcpf(1.0f + E[h]*EY[y*16 + h]), a);
            sc[y] = cst + a;
        }
        Aval = lse15(sc);
        if (pp == d && pp < 15) {
            #pragma unroll
            for (int y = 0; y < 15; y++) gscL[pp*16 + y] = sc[y];
        }
    }
    As[pl*17 + d] = Aval;
    __syncthreads();

    // condensed 4-step transfer matrix per wave (16 waves x 4 steps = 64)
    {
        const int wv = tid >> 6;
        const int ln = tid & 63;
        if (ln < 15) {
            float s[15];
            #pragma unroll
            for (int i = 0; i < 15; i++) s[i] = (i == ln) ? 0.f : NEG;
            const int t0 = wv * 4;
            #pragma unroll
            for (int q = 0; q < 4; q++) {
                const int t = t0 + q;
                float tv[15];
                #pragma unroll
                for (int i = 0; i < 15; i++) tv[i] = s[i] + As[t*17 + i];
                float nw = lse15(tv);
                #pragma unroll
                for (int i = 14; i > 0; i--) s[i] = s[i-1];
                s[0] = nw;
            }
            #pragma unroll
            for (int i = 0; i < 15; i++) Ms[wv*240 + i*16 + ln] = s[i];
        }
    }
    __syncthreads();

    // depth-4 tree combine -> chunk matrix -> T0[block]
    lse_mm(Ms, Mp, 8, tid, 1024);  __syncthreads();
    lse_mm(Mp, Ms, 4, tid, 1024);  __syncthreads();
    lse_mm(Ms, Mp, 2, tid, 1024);  __syncthreads();
    if (tid < 225) {
        const int i = tid / 15, j = tid - (tid / 15) * 15;
        float tv[15];
        #pragma unroll
        for (int k = 0; k < 15; k++) tv[k] = Mp[240 + i*16 + k] + Mp[k*16 + j];
        (ws + OFF_T0)[blockIdx.x*225 + i*15 + j] = lse15(tv);
    }

    // block 0: indiv (gold-score) reduction from LDS gscL -> scalar
    if (blockIdx.x == 0) {
        float loc = 0.f;
        for (int s = tid; s < 2048; s += 1024) {
            int len = p.lengths[s];
            if (len < 15) loc += gscL[(len-1)*16 + p.tags[s]];
        }
        #pragma unroll
        for (int off = 32; off > 0; off >>= 1) loc += __shfl_down(loc, off);
        if ((tid & 63) == 0) red[tid >> 6] = loc;
        __syncthreads();
        if (tid == 0) {
            float ind = 0.f;
            #pragma unroll
            for (int q = 0; q < 16; q++) ind += red[q];
            ws[OFF_IND] = ind;
        }
    }
}

// ============ kD: 16 blocks, group combine (fence-free) =====================
__global__ __launch_bounds__(1024) void kD(Params p)
{
    __shared__ float Ms[16*240];
    __shared__ float Mp[8*240];
    const int tid = threadIdx.x;
    const int g   = blockIdx.x;
    const float* T0 = p.ws + OFF_T0;

    for (int idx = tid; idx < 16*225; idx += 1024) {
        int t = idx / 225, r = idx - t*225;
        Ms[t*240 + (r/15)*16 + (r%15)] = T0[((g<<4) + t)*225 + r];
    }
    __syncthreads();
    lse_mm(Ms, Mp, 8, tid, 1024); __syncthreads();
    lse_mm(Mp, Ms, 4, tid, 1024); __syncthreads();
    lse_mm(Ms, Mp, 2, tid, 1024); __syncthreads();
    if (tid < 225) {
        const int i = tid / 15, j = tid - (tid / 15) * 15;
        float tv[15];
        #pragma unroll
        for (int k = 0; k < 15; k++) tv[k] = Mp[240 + i*16 + k] + Mp[k*16 + j];
        p.ws[OFF_R + g*225 + i*15 + j] = lse15(tv);
    }
}

// ============ kE: 1 block, final combine + output (fence-free) ==============
__global__ __launch_bounds__(1024) void kE(Params p)
{
    __shared__ float Ms[16*240];
    __shared__ float Mp[8*240];
    const int tid = threadIdx.x;
    const float* Rg = p.ws + OFF_R;

    for (int idx = tid; idx < 16*225; idx += 1024) {
        int t = idx / 225, r = idx - t*225;
        Ms[t*240 + (r/15)*16 + (r%15)] = Rg[t*225 + r];
    }
    __syncthreads();
    lse_mm(Ms, Mp, 8, tid, 1024); __syncthreads();
    lse_mm(Mp, Ms, 4, tid, 1024); __syncthreads();
    lse_mm(Ms, Mp, 2, tid, 1024); __syncthreads();
    if (tid == 0) {
        float tv[15];
        #pragma unroll
        for (int k = 0; k < 15; k++) tv[k] = Mp[240 + k] + Mp[k*16];
        float logZ = lse15(tv);
        p.out[0] = logZ - p.ws[OFF_IND];
    }
}

// ================= launcher =================================================
extern "C" void kernel_launch(void* const* d_in, const int* in_sizes, int n_in,
                              void* d_out, int out_size, void* d_ws, size_t ws_size,
                              hipStream_t stream)
{
    Params prm;
    prm.data = (const float*)d_in[0];
    prm.fWih = (const float*)d_in[1];
    prm.fWhh = (const float*)d_in[2];
    prm.fbih = (const float*)d_in[3];
    prm.fbhh = (const float*)d_in[4];
    prm.bWih = (const float*)d_in[5];
    prm.bWhh = (const float*)d_in[6];
    prm.bbih = (const float*)d_in[7];
    prm.bbhh = (const float*)d_in[8];
    prm.h0f  = (const float*)d_in[9];
    prm.c0f  = (const float*)d_in[10];
    prm.h0b  = (const float*)d_in[11];
    prm.c0b  = (const float*)d_in[12];
    prm.Yenc = (const float*)d_in[13];
    prm.Zenc = (const float*)d_in[14];
    prm.VW   = (const float*)d_in[15];
    prm.Vb   = (const float*)d_in[16];
    prm.WW   = (const float*)d_in[17];
    prm.Wb   = (const float*)d_in[18];
    prm.tags    = (const int*)d_in[19];
    prm.lengths = (const int*)d_in[20];
    prm.ws  = (float*)d_ws;
    prm.out = (float*)d_out;

    hipLaunchKernelGGL(kA,  dim3(256, 2), dim3(512),  0, stream, prm);
    hipLaunchKernelGGL(kBC, dim3(256),    dim3(1024), 0, stream, prm);
    hipLaunchKernelGGL(kD,  dim3(16),     dim3(1024), 0, stream, prm);
    hipLaunchKernelGGL(kE,  dim3(1),      dim3(1024), 0, stream, prm);
}